// Round 5
// baseline (539.962 us; speedup 1.0000x reference)
//
#include <hip/hip_runtime.h>

// SRLoss: loss = mean((inp - avgpool10x10(output))^2) + BCE(output, target)
// output/target: [32,1,1280,1280] f32; inp: [32,1,128,128] f32; out: scalar f32.
//
// R4 post-mortem: compiler collapses hand pipelines to ~4 outstanding loads
// (VGPR=44) and 5-wave blocks quantize to ~2 blocks/CU (occ 30%) -> stuck at
// ~5 B/cyc/CU delivered. Delivered BW across R1/R2/R4 tracks bytes-in-flight
// per CU (~40-60 KB). R5: get MLP from TLP instead of per-thread depth:
// 128-thread blocks (2 waves), VGPR<=64 via __launch_bounds__(128,8) ->
// up to 16 blocks = 32 waves/CU. Band per block = exactly 25 float4-pair
// iters/thread, fully unrolled. Pooled-column phase (c mod 320) cycles with
// period 5 -> 5 register accumulator pairs, <=10 LDS atomics post-loop.

#define BATCH 32
#define HH 1280
#define WW 1280
#define PH 128
#define PW 128
#define SC 10
#define NT 128                      // threads per block (2 waves)
#define KD 25                      // float4-pair iterations per thread
#define NPH 5                      // pooled-column phases (lcm(128,320)/128)

static constexpr float EPSV = 1e-20f;
static constexpr float LN2  = 0.6931471805599453f;
static constexpr float INV_NB = 1.0f / (float)(BATCH * HH * WW);   // bce mean
static constexpr float INV_NM = 1.0f / (float)(BATCH * PH * PW);   // mse mean

__global__ __launch_bounds__(NT, 8) void srloss_kernel(
    const float* __restrict__ output,
    const float* __restrict__ target,
    const float* __restrict__ inp,
    float* __restrict__ out)
{
    __shared__ float psum[PW];      // pooled column sums for this band
    __shared__ float red[NT / 64];  // cross-wave reduction scratch

    const int t = threadIdx.x;
    const int band = blockIdx.x;    // 0 .. BATCH*PH-1
    const int b = band >> 7;        // band / 128
    const int pr = band & 127;      // band % 128

    psum[t] = 0.0f;                 // NT == PW == 128
    __syncthreads();

    const size_t base = ((size_t)b * HH + (size_t)pr * SC) * WW;
    const float4* __restrict__ o4p = (const float4*)(output + base) + t;
    const float4* __restrict__ t4p = (const float4*)(target + base) + t;

    float acc2 = 0.0f;              // sum log2(oc)
    float accd = 0.0f;              // sum t*(log2(om)-log2(oc))
    float s0[NPH] = {0, 0, 0, 0, 0};   // pooled sums, first half of float4
    float s1[NPH] = {0, 0, 0, 0, 0};   // pooled sums, second half
    #pragma unroll
    for (int k = 0; k < KD; ++k) {
        const int p = k % NPH;      // compile-time after full unroll
        const float4 o4 = o4p[NT * k];
        const float4 t4 = t4p[NT * k];
        const float o[4]  = {o4.x, o4.y, o4.z, o4.w};
        const float tg[4] = {t4.x, t4.y, t4.z, t4.w};
        #pragma unroll
        for (int j = 0; j < 4; ++j) {
            const float om = fmaxf(o[j], EPSV);
            const float oc = fmaxf(1.0f - o[j], EPSV);
            const float l1 = __log2f(om);
            const float l2 = __log2f(oc);
            acc2 += l2;
            accd += tg[j] * (l1 - l2);
        }
        s0[p] += o[0] + o[1];
        s1[p] += o[2] + o[3];
    }
    const float bce_acc = LN2 * (acc2 + accd);

    // c = t + 128k -> c mod 320 depends only on k mod 5.
    #pragma unroll
    for (int p = 0; p < NPH; ++p) {
        int r = t + NT * p;         // < 640
        if (r >= 320) r -= 320;     // r = c mod 320
        const int col0 = 4 * r;
        const int p0 = col0 / SC;
        if ((col0 % SC) == 8) {     // straddle: second half belongs to p0+1
            atomicAdd(&psum[p0],     s0[p]);
            atomicAdd(&psum[p0 + 1], s1[p]);
        } else {
            atomicAdd(&psum[p0], s0[p] + s1[p]);
        }
    }
    __syncthreads();

    // MSE terms: one pooled element per thread (NT == PW)
    const float pooled = psum[t] * (1.0f / (float)(SC * SC));
    const float iv = inp[(size_t)band * PW + t];
    const float d = iv - pooled;
    const float mse_acc = d * d;

    // per-block contribution, pre-normalized
    float contrib = (-INV_NB) * bce_acc + INV_NM * mse_acc;

    #pragma unroll
    for (int off = 32; off > 0; off >>= 1)
        contrib += __shfl_down(contrib, off, 64);
    if ((t & 63) == 0) red[t >> 6] = contrib;
    __syncthreads();
    if (t == 0) {
        atomicAdd(out, red[0] + red[1]);
    }
}

extern "C" void kernel_launch(void* const* d_in, const int* in_sizes, int n_in,
                              void* d_out, int out_size, void* d_ws, size_t ws_size,
                              hipStream_t stream) {
    const float* output = (const float*)d_in[0];
    const float* target = (const float*)d_in[1];
    const float* inp    = (const float*)d_in[2];
    float* out = (float*)d_out;

    // d_out is poisoned (0xAA) before every timed replay; zero it ourselves.
    hipMemsetAsync(out, 0, sizeof(float), stream);

    srloss_kernel<<<BATCH * PH, NT, 0, stream>>>(output, target, inp, out);
}